// Round 11
// baseline (38.090 us; speedup 1.0000x reference)
//
#include <hip/hip_runtime.h>
#include <math.h>

#define NKEYS 8192
#define NBINS 128
#define NFREQ 64
#define NKER  3
#define HEADD 128

// Fourier expansion: e^{k(cos d - 1)} = e^-k [I0(k) + 2 sum_m Im(k) cos(m d)]
// kappa <= 1. M=3: dropped m=4 term RMS ~4e-3 on logits (threshold 0.152,
// fp16-quant noise already 0.031). Bessel series j<=4: ~1e-8.
#define MHARM 3
#define NCH   7                    // {1, cos m, sin m}, m=1..3
#define KDIM  (NCH * NFREQ)        // 448
#define KSTEPS (KDIM / 32)         // 14 MFMA K-steps

// Fragment-order k-mapping (16x16x32 f16 MFMA, verified rounds 3-10):
//   k_global = kt*32 + q*8 + j  (q = lane>>4, j = 0..7)
//   (ch, f) <-> kt = ch*2 + (f>>5), q = (f>>3)&3, j = f&7   (bijective)

#define BM 32                      // rows per block (2 chunks of 16)
#define GT 256                     // 4 waves; wave w -> 16 cols

typedef _Float16 f16x8 __attribute__((ext_vector_type(8)));
typedef float    f32x4 __attribute__((ext_vector_type(4)));

// ---------------------------------------------------------------------------
// Single fused kernel (R6 structure + no-spill regs + 2 blocks/CU overlap):
//  - A-features -> LDS in fragment order (28,672 B)
//  - B-coefficients recomputed per lane IN REGISTERS (1 col x 16 freqs)
//  - 14 K-steps x 2 row-chunks of 16x16x32 f16 MFMA
// Grid 512 = 256 rowgroups x 2 colhalves -> 2 blocks/CU, 2 waves/SIMD.
// __launch_bounds__(256,2): <=256 VGPR -> bfrag[14] (56 VGPR) stays in regs
// (the (256,4) cap provably spilled in R9/R10: VGPR_Count=52 < afrag size).
// ---------------------------------------------------------------------------
__global__ __launch_bounds__(GT, 2) void fused_all(
    const float* __restrict__ K,
    const float* __restrict__ refang,
    const float* __restrict__ mu,
    const float* __restrict__ kappa,
    const float* __restrict__ weight,
    const float* __restrict__ bias,
    float* __restrict__ out)
{
    __shared__ __align__(16) _Float16 Afrag[2 * KSTEPS * 512];   // 28,672 B

    const int tid  = threadIdx.x;
    const int bid  = blockIdx.x;
    const int row0 = (bid >> 1) * BM;
    const int cblk = bid & 1;                    // which 64-col half

    // ---------------- A prologue: 256 octet jobs, 1 per thread -------------
    {
        const int n  = tid >> 3;                 // row 0..31
        const int oc = tid & 7;                  // freq octet 0..7
        const int qa = oc & 3, half = oc >> 2;
        const int chunk = n >> 4, lcn = n & 15;

        const float4* ldp = (const float4*)(K + (size_t)(row0 + n) * HEADD + oc * 16);
        const float4 p0 = ldp[0], p1 = ldp[1], p2 = ldp[2], p3 = ldp[3];
        const float xs[8] = {p0.x, p0.z, p1.x, p1.z, p2.x, p2.z, p3.x, p3.z};
        const float ys[8] = {p0.y, p0.w, p1.y, p1.w, p2.y, p2.w, p3.y, p3.w};

        float mag[8], c1[8], cc[8], sc[8], cp[8], sp[8];
        f16x8 v;
        #pragma unroll
        for (int i = 0; i < 8; ++i) {
            const float m2 = xs[i] * xs[i] + ys[i] * ys[i];
            const float ri = (m2 > 0.f) ? rsqrtf(m2) : 0.f;
            mag[i] = m2 * ri;
            c1[i] = xs[i] * ri;
            const float s1 = ys[i] * ri;
            cp[i] = 1.f; sp[i] = 0.f; cc[i] = c1[i]; sc[i] = s1;
            v[i] = (_Float16)mag[i];
        }
        // kt = ch*2 + half -> byte offset ch*1024 + half*512 (halfs: ch*512+...)
        _Float16* base = Afrag + chunk * (KSTEPS * 512) + half * 512
                               + (qa * 16 + lcn) * 8;
        *(f16x8*)base = v;                                   // ch 0
        #pragma unroll
        for (int m = 1; m <= MHARM; ++m) {
            f16x8 vc, vs;
            #pragma unroll
            for (int i = 0; i < 8; ++i) {
                vc[i] = (_Float16)(mag[i] * cc[i]);
                vs[i] = (_Float16)(mag[i] * sc[i]);
                const float cn = fmaf(2.f * c1[i], cc[i], -cp[i]);
                const float sn = fmaf(2.f * c1[i], sc[i], -sp[i]);
                cp[i] = cc[i]; sp[i] = sc[i]; cc[i] = cn; sc[i] = sn;
            }
            *(f16x8*)(base + (2 * m - 1) * 1024) = vc;
            *(f16x8*)(base + (2 * m) * 1024)     = vs;
        }
    }

    // ---------------- B coefficients in registers (1 col x 16 freqs) -------
    const int lane = tid & 63, wave = tid >> 6;
    const int q = lane >> 4, lc = lane & 15;
    const int g = cblk * 4 + wave;               // col group 0..7
    const int bin = g * 16 + lc;

    f16x8 bfrag[KSTEPS];
    #pragma unroll
    for (int half = 0; half < 2; ++half) {
        const int fb = half * 32 + q * 8;        // 8 consecutive freqs
        // 24 consecutive floats per array = 8 freqs x 3 kernels, 16B-aligned
        const size_t off = ((size_t)bin * NFREQ + fb) * NKER;
        float4 m4[6], k4[6], w4[6];
        #pragma unroll
        for (int i = 0; i < 6; ++i) {
            m4[i] = ((const float4*)(mu + off))[i];
            k4[i] = ((const float4*)(kappa + off))[i];
            w4[i] = ((const float4*)(weight + off))[i];
        }
        const float* mv = (const float*)m4;
        const float* kv = (const float*)k4;
        const float* wv = (const float*)w4;
        #pragma unroll
        for (int j = 0; j < 8; ++j) {
            const float rf = refang[fb + j];
            float ach[NCH];
            #pragma unroll
            for (int c = 0; c < NCH; ++c) ach[c] = 0.f;
            #pragma unroll
            for (int k = 0; k < NKER; ++k) {
                const float me  = mv[3 * j + k] + rf;
                const float kap = kv[3 * j + k];
                const float w   = wv[3 * j + k];
                const float wek = w * __expf(-kap);
                float s1, c1;
                __sincosf(me, &s1, &c1);
                const float h = 0.5f * kap, h2 = h * h;

                float Im[MHARM + 1];
                float tm = 1.f;                   // h^m / m!
                #pragma unroll
                for (int m = 0; m <= MHARM; ++m) {
                    float t = tm, s = tm;
                    #pragma unroll
                    for (int jj = 1; jj <= 4; ++jj) { t *= h2 / (float)(jj * (m + jj)); s += t; }
                    Im[m] = s;
                    tm *= h / (float)(m + 1);
                }

                ach[0] = fmaf(wek, Im[0], ach[0]);
                float cp = 1.f, sp = 0.f, cc = c1, sc = s1;
                #pragma unroll
                for (int m = 1; m <= MHARM; ++m) {
                    const float gm = 2.f * wek * Im[m];
                    ach[2 * m - 1] = fmaf(gm, cc, ach[2 * m - 1]);
                    ach[2 * m]     = fmaf(gm, sc, ach[2 * m]);
                    const float cn = fmaf(2.f * c1, cc, -cp);
                    const float sn = fmaf(2.f * c1, sc, -sp);
                    cp = cc; sp = sc; cc = cn; sc = sn;
                }
            }
            #pragma unroll
            for (int c = 0; c < NCH; ++c)
                bfrag[c * 2 + half][j] = (_Float16)ach[c];
        }
    }

    __syncthreads();

    // ---------------- GEMM: 14 K-steps x 2 row-chunks, B in VGPRs ----------
    f32x4 acc0 = {0.f, 0.f, 0.f, 0.f};
    f32x4 acc1 = {0.f, 0.f, 0.f, 0.f};
    const f16x8* ap = (const f16x8*)Afrag + lane;       // lane*16B, conflict-free
    #pragma unroll
    for (int kt = 0; kt < KSTEPS; ++kt) {
        const f16x8 a0 = ap[kt * 64];
        const f16x8 a1 = ap[KSTEPS * 64 + kt * 64];
        acc0 = __builtin_amdgcn_mfma_f32_16x16x32_f16(a0, bfrag[kt], acc0, 0, 0, 0);
        acc1 = __builtin_amdgcn_mfma_f32_16x16x32_f16(a1, bfrag[kt], acc1, 0, 0, 0);
    }

    // C/D layout: col = lane&15, row = (lane>>4)*4 + reg
    const int col = g * 16 + lc;
    const float bb = bias[col];
    #pragma unroll
    for (int jj = 0; jj < 4; ++jj) {
        out[(size_t)(row0 + q * 4 + jj) * NBINS + col]      = acc0[jj] + bb;
        out[(size_t)(row0 + 16 + q * 4 + jj) * NBINS + col] = acc1[jj] + bb;
    }
}

// ---------------------------------------------------------------------------
extern "C" void kernel_launch(void* const* d_in, const int* in_sizes, int n_in,
                              void* d_out, int out_size, void* d_ws, size_t ws_size,
                              hipStream_t stream) {
    const float* K      = (const float*)d_in[0];
    const float* refang = (const float*)d_in[1];
    const float* mu     = (const float*)d_in[2];
    const float* kappa  = (const float*)d_in[3];
    const float* weight = (const float*)d_in[4];
    const float* bias   = (const float*)d_in[5];
    float* out = (float*)d_out;

    (void)d_ws; (void)ws_size; (void)in_sizes; (void)n_in; (void)out_size;

    fused_all<<<(NKEYS / BM) * 2, GT, 0, stream>>>(
        K, refang, mu, kappa, weight, bias, out);
}

// Round 12
// 16.871 us; speedup vs baseline: 2.2577x; 2.2577x over previous
//
#include <hip/hip_runtime.h>
#include <math.h>

#define NKEYS 8192
#define NBINS 128
#define NFREQ 64
#define NKER  3
#define HEADD 128

// Fourier expansion: e^{k(cos d - 1)} = e^-k [I0(k) + 2 sum_m Im(k) cos(m d)]
// kappa <= 1, M=3 (R11-verified: absmax 0.03125 vs threshold 0.152).
#define MHARM 3
#define NCH   7                    // {1, cos m, sin m}, m=1..3
#define KDIM  (NCH * NFREQ)        // 448
#define KSTEPS (KDIM / 32)         // 14 MFMA K-steps

// Fragment-order k-mapping (16x16x32 f16 MFMA, verified rounds 3-11):
//   k_global = kt*32 + q*8 + j  (q = lane>>4, j = 0..7)
//   (ch, f) <-> kt = ch*2 + (f>>5), q = (f>>3)&3, j = f&7   (bijective)

typedef _Float16 f16x8 __attribute__((ext_vector_type(8)));
typedef float    f32x4 __attribute__((ext_vector_type(4)));

// ---------------------------------------------------------------------------
// Kernel A: B-coefficient table in fragment order; one thread per (bin,freq),
// each term computed exactly once chip-wide. 32 blocks x 256 thr, ~0.7 us.
// ---------------------------------------------------------------------------
__global__ __launch_bounds__(256) void coeff_kernel(
    const float* __restrict__ refang, const float* __restrict__ mu,
    const float* __restrict__ kappa, const float* __restrict__ weight,
    _Float16* __restrict__ Bswz)
{
    const int gid = blockIdx.x * 256 + threadIdx.x;
    const int b = gid >> 6, f = gid & 63;
    const float rf = refang[f];

    float acc[NCH];
    #pragma unroll
    for (int c = 0; c < NCH; ++c) acc[c] = 0.f;

    #pragma unroll
    for (int k = 0; k < NKER; ++k) {
        const int idx = (b * NFREQ + f) * NKER + k;
        const float me  = mu[idx] + rf;
        const float kap = kappa[idx];
        const float w   = weight[idx];
        const float h = 0.5f * kap, h2 = h * h;
        const float wek = w * __expf(-kap);
        float s1, c1;
        __sincosf(me, &s1, &c1);

        float Im[MHARM + 1];
        float tm = 1.f;                       // h^m / m!
        #pragma unroll
        for (int m = 0; m <= MHARM; ++m) {
            float t = tm, s = tm;
            #pragma unroll
            for (int j = 1; j <= 5; ++j) { t *= h2 / (float)(j * (m + j)); s += t; }
            Im[m] = s;
            tm *= h / (float)(m + 1);
        }

        acc[0] += wek * Im[0];
        float cp = 1.f, sp = 0.f, cc = c1, sc = s1;
        #pragma unroll
        for (int m = 1; m <= MHARM; ++m) {
            const float g = 2.f * wek * Im[m];
            acc[2 * m - 1] += g * cc;
            acc[2 * m]     += g * sc;
            const float cn = fmaf(2.f * c1, cc, -cp);
            const float sn = fmaf(2.f * c1, sc, -sp);
            cp = cc; sp = sc; cc = cn; sc = sn;
        }
    }

    const int g = b >> 4, lc = b & 15;
    const int q = (f >> 3) & 3, j = f & 7;
    #pragma unroll
    for (int c = 0; c < NCH; ++c) {
        const int kt = c * 2 + (f >> 5);
        Bswz[((size_t)(g * KSTEPS + kt) * 64 + q * 16 + lc) * 8 + j] = (_Float16)acc[c];
    }
}

// ---------------------------------------------------------------------------
// Kernel B: GEMM with A-fragments generated ON THE FLY (no persistent operand
// array -> no spill). Per lane per freq: state (c1,s1,C,S), C,S = mag*(cos m,
// sin m); rotate per harmonic and emit in kt = ch*2+half order. Each A-frag
// feeds 2 colgroups (acc0/acc1). 0 LDS, 0 barriers, no transcendentals.
// Block = 4 waves, all on one 16-row chunk (shared K reads); wave w ->
// colgroups {2w, 2w+1}. Grid 512 -> 2 blocks/CU, 8 waves/CU.
// ---------------------------------------------------------------------------
#define EMIT(kt, ARR, h)                                                      \
    {                                                                         \
        f16x8 av;                                                             \
        _Pragma("unroll")                                                     \
        for (int i_ = 0; i_ < 8; ++i_) av[i_] = (_Float16)ARR[h][i_];         \
        const f16x8 b0_ = bp0[(kt) * 64];                                     \
        const f16x8 b1_ = bp1[(kt) * 64];                                     \
        acc0 = __builtin_amdgcn_mfma_f32_16x16x32_f16(av, b0_, acc0, 0, 0, 0);\
        acc1 = __builtin_amdgcn_mfma_f32_16x16x32_f16(av, b1_, acc1, 0, 0, 0);\
    }

__global__ __launch_bounds__(256) void gemm_kernel(
    const float* __restrict__ K, const _Float16* __restrict__ Bswz,
    const float* __restrict__ bias, float* __restrict__ out)
{
    const int tid = threadIdx.x, bid = blockIdx.x;
    const int lane = tid & 63, w = tid >> 6;
    const int rc = bid;                          // row chunk 0..511
    const int g0 = w * 2, g1 = g0 + 1;           // colgroups 0..7
    const int q = lane >> 4, lc = lane & 15;
    const int row = rc * 16 + lc;

    // ---- init rotation state from K: 16 freqs (2 halves x 8) per lane ----
    float mag[2][8], c1[2][8], s1[2][8], C[2][8], S[2][8];
    const float* kp = K + (size_t)row * HEADD + q * 16;
    #pragma unroll
    for (int h = 0; h < 2; ++h) {
        const float4* ldp = (const float4*)(kp + h * 64);
        const float4 p0 = ldp[0], p1 = ldp[1], p2 = ldp[2], p3 = ldp[3];
        const float xs[8] = {p0.x, p0.z, p1.x, p1.z, p2.x, p2.z, p3.x, p3.z};
        const float ys[8] = {p0.y, p0.w, p1.y, p1.w, p2.y, p2.w, p3.y, p3.w};
        #pragma unroll
        for (int i = 0; i < 8; ++i) {
            const float m2 = xs[i] * xs[i] + ys[i] * ys[i];
            const float ri = (m2 > 0.f) ? rsqrtf(m2) : 0.f;
            mag[h][i] = m2 * ri;
            c1[h][i] = xs[i] * ri;
            s1[h][i] = ys[i] * ri;
        }
    }

    const f16x8* bp0 = (const f16x8*)Bswz + (size_t)g0 * (KSTEPS * 64) + lane;
    const f16x8* bp1 = (const f16x8*)Bswz + (size_t)g1 * (KSTEPS * 64) + lane;
    f32x4 acc0 = {0.f, 0.f, 0.f, 0.f};
    f32x4 acc1 = {0.f, 0.f, 0.f, 0.f};

    // ---- 14 K-steps: emit ch0=mag, then rotate (C,S) and emit cos/sin ----
    #pragma unroll
    for (int h = 0; h < 2; ++h) {
        EMIT(h, mag, h);                                     // ch0, kt=h
        #pragma unroll
        for (int i = 0; i < 8; ++i) {                        // m=1
            C[h][i] = mag[h][i] * c1[h][i];
            S[h][i] = mag[h][i] * s1[h][i];
        }
        EMIT(2 + h, C, h);                                   // cos1, kt=2+h
        EMIT(4 + h, S, h);                                   // sin1, kt=4+h
        #pragma unroll
        for (int m = 2; m <= MHARM; ++m) {
            #pragma unroll
            for (int i = 0; i < 8; ++i) {
                const float Cn = C[h][i] * c1[h][i] - S[h][i] * s1[h][i];
                const float Sn = fmaf(S[h][i], c1[h][i], C[h][i] * s1[h][i]);
                C[h][i] = Cn; S[h][i] = Sn;
            }
            EMIT((2 * m - 1) * 2 + h, C, h);                 // cos m
            EMIT((2 * m) * 2 + h, S, h);                     // sin m
        }
    }

    // C/D layout: col = lane&15, row = (lane>>4)*4 + reg
    const float bb0 = bias[g0 * 16 + lc];
    const float bb1 = bias[g1 * 16 + lc];
    #pragma unroll
    for (int jj = 0; jj < 4; ++jj) {
        float* op = out + (size_t)(rc * 16 + q * 4 + jj) * NBINS;
        op[g0 * 16 + lc] = acc0[jj] + bb0;
        op[g1 * 16 + lc] = acc1[jj] + bb1;
    }
}

// ---------------------------------------------------------------------------
// Last-resort fallback (ws too small): direct form, known-correct.
// ---------------------------------------------------------------------------
#define KPB 16
#define FTHREADS 512
#define KPT 4
#define KV_STRIDE (KPB + 1)
#define LOG2E 1.44269504088896340736f

__global__ __launch_bounds__(FTHREADS) void vonmises_fallback(
    const float* __restrict__ K,
    const float* __restrict__ refang,
    const float* __restrict__ mu,
    const float* __restrict__ kappa,
    const float* __restrict__ weight,
    const float* __restrict__ bias,
    float* __restrict__ out)
{
    __shared__ float4 kvlds[NFREQ * KV_STRIDE];
    const int tid  = threadIdx.x;
    const int key0 = blockIdx.x * KPB;

    for (int p = tid; p < KPB * NFREQ; p += FTHREADS) {
        int key = p >> 6, f = p & (NFREQ - 1);
        const float2 xy = *(const float2*)(K + (size_t)(key0 + key) * HEADD + 2 * f);
        float m2 = xy.x * xy.x + xy.y * xy.y;
        float rm = (m2 > 0.f) ? rsqrtf(m2) : 0.f;
        kvlds[f * KV_STRIDE + key] = make_float4(xy.x * rm, xy.y * rm, m2 * rm, 0.f);
    }
    __syncthreads();

    const int bin = tid & (NBINS - 1);
    const int kbase = (tid >> 7) * KPT;
    float acc[KPT] = {0.f, 0.f, 0.f, 0.f};

    for (int f = 0; f < NFREQ; ++f) {
        float4 kv[KPT];
        #pragma unroll
        for (int j = 0; j < KPT; ++j) kv[j] = kvlds[f * KV_STRIDE + kbase + j];
        float wk[KPT] = {0.f, 0.f, 0.f, 0.f};
        #pragma unroll
        for (int k = 0; k < NKER; ++k) {
            int idx = (bin * NFREQ + f) * NKER + k;
            float me = mu[idx] + refang[f];
            float ka = kappa[idx] * LOG2E;
            float s, c;
            __sincosf(me, &s, &c);
            #pragma unroll
            for (int j = 0; j < KPT; ++j) {
                float t = fmaf(kv[j].x, ka * c, fmaf(kv[j].y, ka * s, -ka));
                wk[j] = fmaf(exp2f(t), weight[idx], wk[j]);
            }
        }
        #pragma unroll
        for (int j = 0; j < KPT; ++j) acc[j] = fmaf(wk[j], kv[j].z, acc[j]);
    }
    const float bb = bias[bin];
    #pragma unroll
    for (int j = 0; j < KPT; ++j)
        out[(size_t)(key0 + kbase + j) * NBINS + bin] = acc[j] + bb;
}

// ---------------------------------------------------------------------------
extern "C" void kernel_launch(void* const* d_in, const int* in_sizes, int n_in,
                              void* d_out, int out_size, void* d_ws, size_t ws_size,
                              hipStream_t stream) {
    const float* K      = (const float*)d_in[0];
    const float* refang = (const float*)d_in[1];
    const float* mu     = (const float*)d_in[2];
    const float* kappa  = (const float*)d_in[3];
    const float* weight = (const float*)d_in[4];
    const float* bias   = (const float*)d_in[5];
    float* out = (float*)d_out;

    const size_t need = (size_t)NBINS * KDIM * sizeof(_Float16);   // 112 KiB

    if (ws_size >= need) {
        _Float16* Bswz = (_Float16*)d_ws;
        coeff_kernel<<<32, 256, 0, stream>>>(refang, mu, kappa, weight, Bswz);
        gemm_kernel<<<512, 256, 0, stream>>>(K, Bswz, bias, out);
    } else {
        vonmises_fallback<<<NKEYS / KPB, FTHREADS, 0, stream>>>(
            K, refang, mu, kappa, weight, bias, out);
    }
}